// Round 12
// baseline (223.266 us; speedup 1.0000x reference)
//
#include <hip/hip_runtime.h>
#include <hip/hip_fp16.h>

#define NN 100000
#define NE 3200000
#define NG 2048
#define HD 64
#define BUKSZ 256         // nodes per bucket
#define NBUK 391          // ceil(NN / BUKSZ)
#define NB 512            // stage blocks
#define CHUNK 6250        // NE / NB exactly
#define CAP 9216          // padded edge capacity per bucket (mean 8192, sigma ~90)

// NOTE: int LDS atomics only (native ds ops). Float LDS atomicAdd is a CAS
// loop on this target (R8: 204.8M of them = 1342us) -- never use it.
// NOTE2 (R9): latency-bound gathers want max independent waves; do not make
// one wave process multiple nodes behind a block barrier.
// NOTE3 (R11): shfl with divergent srcLane inside half-divergent loops broke
// correctness (absmax 1.2e-2). Direct index loads only until isolated.

// ---------------- init per-bucket cursors (absolute) ----------------

__global__ void init_k(int* __restrict__ bcur) {
    int t = blockIdx.x * blockDim.x + threadIdx.x;
    if (t <= NBUK) bcur[t] = t * CAP;
}

// ---------------- pass 1: block-local bucket sort -> padded bucket runs ----------------
// packed value: (dst & 255) << 17 | src   (src < 2^17)

__global__ __launch_bounds__(512) void stageA_k(
        const int* __restrict__ src, const int* __restrict__ dst,
        int* __restrict__ bcur, unsigned int* __restrict__ edges2) {
    __shared__ int hist[NBUK];
    __shared__ int exb[NBUK + 1];
    __shared__ int cur[NBUK];
    __shared__ int obase[NBUK];
    __shared__ int sc[512];
    __shared__ unsigned int svals[CHUNK];
    int b = blockIdx.x, t = threadIdx.x;
    int base = b * CHUNK;
    for (int i = t; i < NBUK; i += 512) hist[i] = 0;
    __syncthreads();
    for (int i = t; i < CHUNK; i += 512)
        atomicAdd(&hist[dst[base + i] >> 8], 1);
    __syncthreads();
    int v = (t < NBUK) ? hist[t] : 0;
    sc[t] = v;
    __syncthreads();
    for (int o = 1; o < 512; o <<= 1) {
        int u = (t >= o) ? sc[t - o] : 0;
        __syncthreads();
        sc[t] += u;
        __syncthreads();
    }
    if (t < NBUK) {
        int excl = sc[t] - v;
        exb[t] = excl;
        cur[t] = excl;
        obase[t] = v ? atomicAdd(&bcur[t], v) : 0;
    }
    if (t == 0) exb[NBUK] = CHUNK;
    __syncthreads();
    // scatter into LDS bucket-sorted order
    for (int i = t; i < CHUNK; i += 512) {
        int d = dst[base + i];
        int s = src[base + i];
        int pos = atomicAdd(&cur[d >> 8], 1);
        svals[pos] = ((unsigned int)(d & 255) << 17) | (unsigned int)s;
    }
    __syncthreads();
    // copy out: slot i -> bucket via LDS binary search; coalesced runs
    for (int i = t; i < CHUNK; i += 512) {
        int lo = 0, hi = NBUK;            // exb[lo] <= i < exb[hi]
        while (hi - lo > 1) {
            int mid = (lo + hi) >> 1;
            if (exb[mid] <= i) lo = mid; else hi = mid;
        }
        edges2[obase[lo] + (i - exb[lo])] = svals[i];
    }
}

// ---------------- pass 2: per-bucket fine sort (in-place) + row info + dinv + xs ----------------

__global__ __launch_bounds__(512) void build1_k(
        const int* __restrict__ bcur, const float4* __restrict__ x,
        unsigned int* __restrict__ edges2, int* __restrict__ row_beg,
        int* __restrict__ row_deg, float* __restrict__ dinv,
        float4* __restrict__ xs) {
    __shared__ unsigned int ebuf[CAP];   // 36 KB
    __shared__ int deg[BUKSZ];
    __shared__ int sc[BUKSZ];
    __shared__ int cur[BUKSZ];
    int k = blockIdx.x, t = threadIdx.x;
    int base = k * CAP;
    int len = bcur[k] - base;
    if (t < BUKSZ) deg[t] = 0;
    __syncthreads();
    for (int i = t; i < len; i += 512) {
        unsigned int pv = edges2[base + i];
        ebuf[i] = pv;
        atomicAdd(&deg[pv >> 17], 1);
    }
    __syncthreads();
    int v = 0;
    if (t < BUKSZ) { v = deg[t]; sc[t] = v; }
    __syncthreads();
    for (int o = 1; o < BUKSZ; o <<= 1) {
        int u = 0;
        if (t < BUKSZ && t >= o) u = sc[t - o];
        __syncthreads();
        if (t < BUKSZ && t >= o) sc[t] += u;
        __syncthreads();
    }
    if (t < BUKSZ) {
        int excl = sc[t] - v;
        cur[t] = excl;
        int node = k * BUKSZ + t;
        if (node < NN) {
            row_beg[node] = base + excl;
            row_deg[node] = v;
            float di = rsqrtf((float)v + 1.0f);
            dinv[node] = di;
            float4 xv = x[node];
            xs[node] = make_float4(xv.x * di, xv.y * di, xv.z * di, xv.w * di);
        }
    }
    __syncthreads();
    for (int i = t; i < len; i += 512) {
        unsigned int pv = ebuf[i];
        int pos = atomicAdd(&cur[pv >> 17], 1);
        edges2[base + pos] = pv & 0x1FFFFu;
    }
}

// ---------------- layer 1 FUSED: wave-per-node gather + W1 GEMM -> fp16 h1 ----------------
// h1[node][h] = fp16( dinv * relu( (dinv*(sum xs[src] + xs[node])) @ W1 + b1 ) )

__global__ __launch_bounds__(256) void g1f_k(
        const float4* __restrict__ xs, const unsigned int* __restrict__ csr,
        const int* __restrict__ row_beg, const int* __restrict__ row_deg,
        const float* __restrict__ dinv, const float* __restrict__ W1,
        const float* __restrict__ b1, __half* __restrict__ h1) {
    int wid = (blockIdx.x * blockDim.x + threadIdx.x) >> 6;
    int lane = threadIdx.x & 63;
    if (wid >= NN) return;
    int beg = row_beg[wid], deg = row_deg[wid];
    float sx = 0.f, sy = 0.f, sz = 0.f, sw = 0.f;
    for (int e = beg + lane; e < beg + deg; e += 64) {
        float4 w = xs[csr[e]];
        sx += w.x; sy += w.y; sz += w.z; sw += w.w;
    }
#pragma unroll
    for (int o = 1; o < 64; o <<= 1) {
        sx += __shfl_xor(sx, o);
        sy += __shfl_xor(sy, o);
        sz += __shfl_xor(sz, o);
        sw += __shfl_xor(sw, o);
    }
    float di = dinv[wid];
    float4 self = xs[wid];
    float ax = (sx + self.x) * di;
    float ay = (sy + self.y) * di;
    float az = (sz + self.z) * di;
    float aw = (sw + self.w) * di;
    float v = ax * W1[lane] + ay * W1[64 + lane] + az * W1[128 + lane] + aw * W1[192 + lane] + b1[lane];
    v = fmaxf(v, 0.f) * di;
    h1[(size_t)wid * HD + lane] = __float2half_rn(v);
}

// ---------------- layer 2 gather: wave = 1 dst node, 8 edges/half-wave/iter (R10 proven) ----------------

__global__ void gather2_k(const __half* __restrict__ h1, const unsigned int* __restrict__ csr,
                          const int* __restrict__ row_beg, const int* __restrict__ row_deg,
                          float* __restrict__ a2) {
    int wid = (blockIdx.x * blockDim.x + threadIdx.x) >> 6;
    int lane = threadIdx.x & 63;
    if (wid >= NN) return;
    int half = lane >> 5, f2 = lane & 31;
    int beg = row_beg[wid], end = beg + row_deg[wid];
    float ax = 0.f, ay = 0.f;
    int e = beg + half;
    for (; e + 14 < end; e += 16) {        // 8 edges per half per iter
        int s0 = csr[e],      s1 = csr[e + 2];
        int s2 = csr[e + 4],  s3 = csr[e + 6];
        int s4 = csr[e + 8],  s5 = csr[e + 10];
        int s6 = csr[e + 12], s7 = csr[e + 14];
        float2 f0 = __half22float2(((const __half2*)(h1 + (size_t)s0 * HD))[f2]);
        float2 f1 = __half22float2(((const __half2*)(h1 + (size_t)s1 * HD))[f2]);
        float2 f3 = __half22float2(((const __half2*)(h1 + (size_t)s2 * HD))[f2]);
        float2 f4 = __half22float2(((const __half2*)(h1 + (size_t)s3 * HD))[f2]);
        float2 f5 = __half22float2(((const __half2*)(h1 + (size_t)s4 * HD))[f2]);
        float2 f6 = __half22float2(((const __half2*)(h1 + (size_t)s5 * HD))[f2]);
        float2 f7 = __half22float2(((const __half2*)(h1 + (size_t)s6 * HD))[f2]);
        float2 f8 = __half22float2(((const __half2*)(h1 + (size_t)s7 * HD))[f2]);
        ax += ((f0.x + f1.x) + (f3.x + f4.x)) + ((f5.x + f6.x) + (f7.x + f8.x));
        ay += ((f0.y + f1.y) + (f3.y + f4.y)) + ((f5.y + f6.y) + (f7.y + f8.y));
    }
    for (; e + 2 < end; e += 4) {
        int s0 = csr[e], s1 = csr[e + 2];
        float2 f0 = __half22float2(((const __half2*)(h1 + (size_t)s0 * HD))[f2]);
        float2 f1 = __half22float2(((const __half2*)(h1 + (size_t)s1 * HD))[f2]);
        ax += f0.x + f1.x;
        ay += f0.y + f1.y;
    }
    for (; e < end; e += 2) {
        int s0 = csr[e];
        float2 f0 = __half22float2(((const __half2*)(h1 + (size_t)s0 * HD))[f2]);
        ax += f0.x; ay += f0.y;
    }
    ax += __shfl_xor(ax, 32);
    ay += __shfl_xor(ay, 32);
    float2 self = __half22float2(((const __half2*)(h1 + (size_t)wid * HD))[f2]);
    ax += self.x; ay += self.y;
    if (half == 0)
        ((float2*)(a2 + (size_t)wid * HD))[f2] = make_float2(ax, ay);
}

// ---------------- combine2 + pool: 32 nodes per 512-thread block ----------------

__global__ __launch_bounds__(512) void combine2_pool_k(
        const float* __restrict__ a2, const float* __restrict__ W2,
        const float* __restrict__ b2, const float* __restrict__ dinv,
        const int* __restrict__ batch, float* __restrict__ pool) {
    __shared__ float w2s[HD * HD];     // 16 KB
    __shared__ float as2[32][HD];      // 8 KB
    __shared__ float vals[32][HD];     // 8 KB
    __shared__ int   bt[32];
    int tid = threadIdx.x;
    int wave = tid >> 6, lane = tid & 63;
    int base = blockIdx.x * 32;
    for (int i = tid; i < HD * HD; i += 512) w2s[i] = W2[i];
    for (int i = tid; i < 32 * HD; i += 512) as2[i >> 6][i & 63] = a2[(size_t)base * HD + i];
    if (tid < 32) bt[tid] = batch[base + tid];
    __syncthreads();
#pragma unroll
    for (int r = 0; r < 4; ++r) {
        int nl = wave * 4 + r;
        float s = 0.f;
#pragma unroll
        for (int k = 0; k < HD; ++k) s = fmaf(as2[nl][k], w2s[k * HD + lane], s);
        float v = fmaxf(fmaf(dinv[base + nl], s, b2[lane]), 0.f);
        vals[nl][lane] = v;
    }
    __syncthreads();
    if (wave == 0) {   // batch-sorted flush: few native global float atomics
        int g = bt[0];
        float acc = 0.f;
        for (int i = 0; i < 32; ++i) {
            int bg = bt[i];
            if (bg != g) { atomicAdd(&pool[g * HD + lane], acc); acc = 0.f; g = bg; }
            acc += vals[i][lane];
        }
        atomicAdd(&pool[g * HD + lane], acc);
    }
}

__device__ __forceinline__ int lb_dev(const int* __restrict__ b, int n, int key) {
    int lo = 0, hi = n;
    while (lo < hi) {
        int mid = (lo + hi) >> 1;
        if (b[mid] < key) lo = mid + 1; else hi = mid;
    }
    return lo;
}

__global__ void final_k(const float* __restrict__ pool, const int* __restrict__ batch,
                        const float* __restrict__ Wlin, const float* __restrict__ blin,
                        float* __restrict__ out) {
    int g = blockIdx.x;
    int lane = threadIdx.x;
    int lo = lb_dev(batch, NN, g);
    int hi = lb_dev(batch, NN, g + 1);
    float cnt = (float)(hi - lo);
    float v = pool[g * HD + lane] * Wlin[lane];
#pragma unroll
    for (int off = 32; off > 0; off >>= 1) v += __shfl_down(v, off);
    if (lane == 0) out[g] = v / fmaxf(cnt, 1.0f) + blin[0];
}

// ---------------- launch ----------------

extern "C" void kernel_launch(void* const* d_in, const int* in_sizes, int n_in,
                              void* d_out, int out_size, void* d_ws, size_t ws_size,
                              hipStream_t stream) {
    const float* x    = (const float*)d_in[0];
    const int*   ei   = (const int*)d_in[1];
    const int*   bat  = (const int*)d_in[2];
    const float* W1   = (const float*)d_in[3];
    const float* b1   = (const float*)d_in[4];
    const float* W2   = (const float*)d_in[5];
    const float* b2   = (const float*)d_in[6];
    const float* Wlin = (const float*)d_in[7];
    const float* blin = (const float*)d_in[8];
    float* out = (float*)d_out;

    const int* src = ei;
    const int* dst = ei + NE;

    char* ws = (char*)d_ws;
    size_t off = 0;
    auto alloc = [&](size_t bytes) {
        char* p = ws + off;
        off += (bytes + 255) & ~(size_t)255;
        return p;
    };
    int*   bcur    = (int*)  alloc((NBUK + 1) * sizeof(int));
    int*   row_beg = (int*)  alloc(NN * sizeof(int));
    int*   row_deg = (int*)  alloc(NN * sizeof(int));
    float* dinv    = (float*)alloc(NN * sizeof(float));
    unsigned int* edges2 = (unsigned int*)alloc((size_t)NBUK * CAP * sizeof(unsigned int)); // 14.4 MB
    float4* xs     = (float4*)alloc((size_t)NN * sizeof(float4));
    __half* h1     = (__half*)alloc((size_t)NN * HD * sizeof(__half));
    float* a2      = (float*)alloc((size_t)NN * HD * sizeof(float));
    float* pool    = (float*)alloc((size_t)NG * HD * sizeof(float));
    (void)ws_size; (void)n_in; (void)in_sizes; (void)out_size;

    const int BLK = 256;
    const int gW = (NN * 64 + BLK - 1) / BLK;   // one wave per node

    // build: bucket runs -> in-place fine sort
    init_k<<<(NBUK + 1 + 255) / 256, 256, 0, stream>>>(bcur);
    stageA_k<<<NB, 512, 0, stream>>>(src, dst, bcur, edges2);
    build1_k<<<NBUK, 512, 0, stream>>>(bcur, (const float4*)x, edges2,
                                       row_beg, row_deg, dinv, xs);

    // layer 1 fused: gather + W1 GEMM -> fp16 h1
    g1f_k<<<gW, BLK, 0, stream>>>(xs, edges2, row_beg, row_deg, dinv, W1, b1, h1);

    // layer 2: direct-load gather -> a2
    gather2_k<<<gW, BLK, 0, stream>>>(h1, edges2, row_beg, row_deg, a2);

    // combine + pool + readout
    hipMemsetAsync(pool, 0, (size_t)NG * HD * sizeof(float), stream);
    combine2_pool_k<<<NN / 32, 512, 0, stream>>>(a2, W2, b2, dinv, bat, pool);
    final_k<<<NG, 64, 0, stream>>>(pool, bat, Wlin, blin, out);
}

// Round 13
// 218.471 us; speedup vs baseline: 1.0219x; 1.0219x over previous
//
#include <hip/hip_runtime.h>
#include <hip/hip_fp16.h>

#define NN 100000
#define NE 3200000
#define NG 2048
#define HD 64
#define BUKSZ 256         // nodes per bucket
#define NBUK 391          // ceil(NN / BUKSZ)
#define NB 512            // stage blocks
#define CHUNK 6250        // NE / NB exactly
#define CAP 9216          // padded edge capacity per bucket (mean 8192, sigma ~90)

// NOTE: int LDS atomics only (native ds ops). Float LDS atomicAdd is a CAS
// loop on this target (R8: 204.8M of them = 1342us) -- never use it.
// NOTE2 (R9): latency-bound gathers want max independent waves; do not make
// one wave process multiple nodes behind a block barrier.
// NOTE3 (R11): shfl with divergent srcLane under half-divergent loop bounds is
// undefined (reads exec-masked lanes). Index preload via wave-private LDS with
// UNIFORM trip counts instead (R13).

// ---------------- init per-bucket cursors (absolute) ----------------

__global__ void init_k(int* __restrict__ bcur) {
    int t = blockIdx.x * blockDim.x + threadIdx.x;
    if (t <= NBUK) bcur[t] = t * CAP;
}

// ---------------- pass 1: block-local bucket sort -> padded bucket runs ----------------
// packed value: (dst & 255) << 17 | src   (src < 2^17)

__global__ __launch_bounds__(512) void stageA_k(
        const int* __restrict__ src, const int* __restrict__ dst,
        int* __restrict__ bcur, unsigned int* __restrict__ edges2) {
    __shared__ int hist[NBUK];
    __shared__ int exb[NBUK + 1];
    __shared__ int cur[NBUK];
    __shared__ int obase[NBUK];
    __shared__ int sc[512];
    __shared__ unsigned int svals[CHUNK];
    int b = blockIdx.x, t = threadIdx.x;
    int base = b * CHUNK;
    for (int i = t; i < NBUK; i += 512) hist[i] = 0;
    __syncthreads();
    for (int i = t; i < CHUNK; i += 512)
        atomicAdd(&hist[dst[base + i] >> 8], 1);
    __syncthreads();
    int v = (t < NBUK) ? hist[t] : 0;
    sc[t] = v;
    __syncthreads();
    for (int o = 1; o < 512; o <<= 1) {
        int u = (t >= o) ? sc[t - o] : 0;
        __syncthreads();
        sc[t] += u;
        __syncthreads();
    }
    if (t < NBUK) {
        int excl = sc[t] - v;
        exb[t] = excl;
        cur[t] = excl;
        obase[t] = v ? atomicAdd(&bcur[t], v) : 0;
    }
    if (t == 0) exb[NBUK] = CHUNK;
    __syncthreads();
    // scatter into LDS bucket-sorted order
    for (int i = t; i < CHUNK; i += 512) {
        int d = dst[base + i];
        int s = src[base + i];
        int pos = atomicAdd(&cur[d >> 8], 1);
        svals[pos] = ((unsigned int)(d & 255) << 17) | (unsigned int)s;
    }
    __syncthreads();
    // copy out: slot i -> bucket via LDS binary search; coalesced runs
    for (int i = t; i < CHUNK; i += 512) {
        int lo = 0, hi = NBUK;            // exb[lo] <= i < exb[hi]
        while (hi - lo > 1) {
            int mid = (lo + hi) >> 1;
            if (exb[mid] <= i) lo = mid; else hi = mid;
        }
        edges2[obase[lo] + (i - exb[lo])] = svals[i];
    }
}

// ---------------- pass 2: per-bucket fine sort (in-place) + row info + dinv + xs ----------------

__global__ __launch_bounds__(512) void build1_k(
        const int* __restrict__ bcur, const float4* __restrict__ x,
        unsigned int* __restrict__ edges2, int* __restrict__ row_beg,
        int* __restrict__ row_deg, float* __restrict__ dinv,
        float4* __restrict__ xs) {
    __shared__ unsigned int ebuf[CAP];   // 36 KB
    __shared__ int deg[BUKSZ];
    __shared__ int sc[BUKSZ];
    __shared__ int cur[BUKSZ];
    int k = blockIdx.x, t = threadIdx.x;
    int base = k * CAP;
    int len = bcur[k] - base;
    if (t < BUKSZ) deg[t] = 0;
    __syncthreads();
    for (int i = t; i < len; i += 512) {
        unsigned int pv = edges2[base + i];
        ebuf[i] = pv;
        atomicAdd(&deg[pv >> 17], 1);
    }
    __syncthreads();
    int v = 0;
    if (t < BUKSZ) { v = deg[t]; sc[t] = v; }
    __syncthreads();
    for (int o = 1; o < BUKSZ; o <<= 1) {
        int u = 0;
        if (t < BUKSZ && t >= o) u = sc[t - o];
        __syncthreads();
        if (t < BUKSZ && t >= o) sc[t] += u;
        __syncthreads();
    }
    if (t < BUKSZ) {
        int excl = sc[t] - v;
        cur[t] = excl;
        int node = k * BUKSZ + t;
        if (node < NN) {
            row_beg[node] = base + excl;
            row_deg[node] = v;
            float di = rsqrtf((float)v + 1.0f);
            dinv[node] = di;
            float4 xv = x[node];
            xs[node] = make_float4(xv.x * di, xv.y * di, xv.z * di, xv.w * di);
        }
    }
    __syncthreads();
    for (int i = t; i < len; i += 512) {
        unsigned int pv = ebuf[i];
        int pos = atomicAdd(&cur[pv >> 17], 1);
        edges2[base + pos] = pv & 0x1FFFFu;
    }
}

// ---------------- layer 1 FUSED: wave-per-node gather + W1 GEMM -> fp16 h1 ----------------

__global__ __launch_bounds__(256) void g1f_k(
        const float4* __restrict__ xs, const unsigned int* __restrict__ csr,
        const int* __restrict__ row_beg, const int* __restrict__ row_deg,
        const float* __restrict__ dinv, const float* __restrict__ W1,
        const float* __restrict__ b1, __half* __restrict__ h1) {
    int wid = (blockIdx.x * blockDim.x + threadIdx.x) >> 6;
    int lane = threadIdx.x & 63;
    if (wid >= NN) return;
    int beg = row_beg[wid], deg = row_deg[wid];
    float sx = 0.f, sy = 0.f, sz = 0.f, sw = 0.f;
    for (int e = beg + lane; e < beg + deg; e += 64) {
        float4 w = xs[csr[e]];
        sx += w.x; sy += w.y; sz += w.z; sw += w.w;
    }
#pragma unroll
    for (int o = 1; o < 64; o <<= 1) {
        sx += __shfl_xor(sx, o);
        sy += __shfl_xor(sy, o);
        sz += __shfl_xor(sz, o);
        sw += __shfl_xor(sw, o);
    }
    float di = dinv[wid];
    float4 self = xs[wid];
    float ax = (sx + self.x) * di;
    float ay = (sy + self.y) * di;
    float az = (sz + self.z) * di;
    float aw = (sw + self.w) * di;
    float v = ax * W1[lane] + ay * W1[64 + lane] + az * W1[128 + lane] + aw * W1[192 + lane] + b1[lane];
    v = fmaxf(v, 0.f) * di;
    h1[(size_t)wid * HD + lane] = __float2half_rn(v);
}

// ---------------- layer 2 gather: wave per node; indices via wave-private LDS ----------------
// a2h[d][h] = fp16( sum_{s in N(d)} h1[s][h] + h1[d][h] )   (fp32 accum, fp16 store)
// All loop bounds are wave-uniform (chunk), so no divergent cross-lane reads.

__global__ __launch_bounds__(256) void gather2_k(
        const __half* __restrict__ h1, const unsigned int* __restrict__ csr,
        const int* __restrict__ row_beg, const int* __restrict__ row_deg,
        __half2* __restrict__ a2h) {
    __shared__ int sidx[4][64];          // per-wave index slice (wave-private)
    int wv = threadIdx.x >> 6;
    int wid = (blockIdx.x * blockDim.x + threadIdx.x) >> 6;
    int lane = threadIdx.x & 63;
    if (wid >= NN) return;
    int half = lane >> 5, f2 = lane & 31;
    int beg = row_beg[wid], deg = row_deg[wid];
    float ax = 0.f, ay = 0.f;
    int done = 0;
    while (done < deg) {
        int chunk = deg - done;
        if (chunk > 64) chunk = 64;
        if (lane < chunk) sidx[wv][lane] = (int)csr[beg + done + lane];  // 1 coalesced load
        int kb = 0;
        for (; kb + 15 < chunk; kb += 16) {   // uniform: 8 edges per half per iter
            int s0 = sidx[wv][kb + half];
            int s1 = sidx[wv][kb + half + 2];
            int s2 = sidx[wv][kb + half + 4];
            int s3 = sidx[wv][kb + half + 6];
            int s4 = sidx[wv][kb + half + 8];
            int s5 = sidx[wv][kb + half + 10];
            int s6 = sidx[wv][kb + half + 12];
            int s7 = sidx[wv][kb + half + 14];
            float2 f0 = __half22float2(((const __half2*)(h1 + (size_t)s0 * HD))[f2]);
            float2 f1 = __half22float2(((const __half2*)(h1 + (size_t)s1 * HD))[f2]);
            float2 f2v = __half22float2(((const __half2*)(h1 + (size_t)s2 * HD))[f2]);
            float2 f3 = __half22float2(((const __half2*)(h1 + (size_t)s3 * HD))[f2]);
            float2 f4 = __half22float2(((const __half2*)(h1 + (size_t)s4 * HD))[f2]);
            float2 f5 = __half22float2(((const __half2*)(h1 + (size_t)s5 * HD))[f2]);
            float2 f6 = __half22float2(((const __half2*)(h1 + (size_t)s6 * HD))[f2]);
            float2 f7 = __half22float2(((const __half2*)(h1 + (size_t)s7 * HD))[f2]);
            ax += ((f0.x + f1.x) + (f2v.x + f3.x)) + ((f4.x + f5.x) + (f6.x + f7.x));
            ay += ((f0.y + f1.y) + (f2v.y + f3.y)) + ((f4.y + f5.y) + (f6.y + f7.y));
        }
        for (; kb + 1 < chunk; kb += 2) {     // uniform: 1 edge per half per iter
            int s0 = sidx[wv][kb + half];
            float2 f0 = __half22float2(((const __half2*)(h1 + (size_t)s0 * HD))[f2]);
            ax += f0.x; ay += f0.y;
        }
        if (kb < chunk && half == 0) {        // odd last edge: half0 only, no cross-lane
            int s0 = sidx[wv][kb];
            float2 f0 = __half22float2(((const __half2*)(h1 + (size_t)s0 * HD))[f2]);
            ax += f0.x; ay += f0.y;
        }
        done += chunk;
    }
    ax += __shfl_xor(ax, 32);
    ay += __shfl_xor(ay, 32);
    float2 self = __half22float2(((const __half2*)(h1 + (size_t)wid * HD))[f2]);
    ax += self.x; ay += self.y;
    if (half == 0)
        a2h[(size_t)wid * 32 + f2] = __floats2half2_rn(ax, ay);
}

// ---------------- combine2 + pool: 32 nodes per 512-thread block (fp16 a2 in) ----------------

__global__ __launch_bounds__(512) void combine2_pool_k(
        const __half* __restrict__ a2h, const float* __restrict__ W2,
        const float* __restrict__ b2, const float* __restrict__ dinv,
        const int* __restrict__ batch, float* __restrict__ pool) {
    __shared__ float w2s[HD * HD];     // 16 KB
    __shared__ float as2[32][HD];      // 8 KB
    __shared__ float vals[32][HD];     // 8 KB
    __shared__ int   bt[32];
    int tid = threadIdx.x;
    int wave = tid >> 6, lane = tid & 63;
    int base = blockIdx.x * 32;
    for (int i = tid; i < HD * HD; i += 512) w2s[i] = W2[i];
    for (int i = tid; i < 32 * HD; i += 512)
        as2[i >> 6][i & 63] = __half2float(a2h[(size_t)base * HD + i]);
    if (tid < 32) bt[tid] = batch[base + tid];
    __syncthreads();
#pragma unroll
    for (int r = 0; r < 4; ++r) {
        int nl = wave * 4 + r;
        float s = 0.f;
#pragma unroll
        for (int k = 0; k < HD; ++k) s = fmaf(as2[nl][k], w2s[k * HD + lane], s);
        float v = fmaxf(fmaf(dinv[base + nl], s, b2[lane]), 0.f);
        vals[nl][lane] = v;
    }
    __syncthreads();
    if (wave == 0) {   // batch-sorted flush: few native global float atomics
        int g = bt[0];
        float acc = 0.f;
        for (int i = 0; i < 32; ++i) {
            int bg = bt[i];
            if (bg != g) { atomicAdd(&pool[g * HD + lane], acc); acc = 0.f; g = bg; }
            acc += vals[i][lane];
        }
        atomicAdd(&pool[g * HD + lane], acc);
    }
}

__device__ __forceinline__ int lb_dev(const int* __restrict__ b, int n, int key) {
    int lo = 0, hi = n;
    while (lo < hi) {
        int mid = (lo + hi) >> 1;
        if (b[mid] < key) lo = mid + 1; else hi = mid;
    }
    return lo;
}

__global__ void final_k(const float* __restrict__ pool, const int* __restrict__ batch,
                        const float* __restrict__ Wlin, const float* __restrict__ blin,
                        float* __restrict__ out) {
    int g = blockIdx.x;
    int lane = threadIdx.x;
    int lo = lb_dev(batch, NN, g);
    int hi = lb_dev(batch, NN, g + 1);
    float cnt = (float)(hi - lo);
    float v = pool[g * HD + lane] * Wlin[lane];
#pragma unroll
    for (int off = 32; off > 0; off >>= 1) v += __shfl_down(v, off);
    if (lane == 0) out[g] = v / fmaxf(cnt, 1.0f) + blin[0];
}

// ---------------- launch ----------------

extern "C" void kernel_launch(void* const* d_in, const int* in_sizes, int n_in,
                              void* d_out, int out_size, void* d_ws, size_t ws_size,
                              hipStream_t stream) {
    const float* x    = (const float*)d_in[0];
    const int*   ei   = (const int*)d_in[1];
    const int*   bat  = (const int*)d_in[2];
    const float* W1   = (const float*)d_in[3];
    const float* b1   = (const float*)d_in[4];
    const float* W2   = (const float*)d_in[5];
    const float* b2   = (const float*)d_in[6];
    const float* Wlin = (const float*)d_in[7];
    const float* blin = (const float*)d_in[8];
    float* out = (float*)d_out;

    const int* src = ei;
    const int* dst = ei + NE;

    char* ws = (char*)d_ws;
    size_t off = 0;
    auto alloc = [&](size_t bytes) {
        char* p = ws + off;
        off += (bytes + 255) & ~(size_t)255;
        return p;
    };
    int*   bcur    = (int*)  alloc((NBUK + 1) * sizeof(int));
    int*   row_beg = (int*)  alloc(NN * sizeof(int));
    int*   row_deg = (int*)  alloc(NN * sizeof(int));
    float* dinv    = (float*)alloc(NN * sizeof(float));
    unsigned int* edges2 = (unsigned int*)alloc((size_t)NBUK * CAP * sizeof(unsigned int)); // 14.4 MB
    float4* xs     = (float4*)alloc((size_t)NN * sizeof(float4));
    __half* h1     = (__half*)alloc((size_t)NN * HD * sizeof(__half));
    __half* a2h    = (__half*)alloc((size_t)NN * HD * sizeof(__half));
    float* pool    = (float*)alloc((size_t)NG * HD * sizeof(float));
    (void)ws_size; (void)n_in; (void)in_sizes; (void)out_size;

    const int BLK = 256;
    const int gW = (NN * 64 + BLK - 1) / BLK;   // one wave per node

    // build: bucket runs -> in-place fine sort
    init_k<<<(NBUK + 1 + 255) / 256, 256, 0, stream>>>(bcur);
    stageA_k<<<NB, 512, 0, stream>>>(src, dst, bcur, edges2);
    build1_k<<<NBUK, 512, 0, stream>>>(bcur, (const float4*)x, edges2,
                                       row_beg, row_deg, dinv, xs);

    // layer 1 fused: gather + W1 GEMM -> fp16 h1
    g1f_k<<<gW, BLK, 0, stream>>>(xs, edges2, row_beg, row_deg, dinv, W1, b1, h1);

    // layer 2: LDS-index gather -> fp16 a2
    gather2_k<<<gW, BLK, 0, stream>>>(h1, edges2, row_beg, row_deg, (__half2*)a2h);

    // combine + pool + readout
    hipMemsetAsync(pool, 0, (size_t)NG * HD * sizeof(float), stream);
    combine2_pool_k<<<NN / 32, 512, 0, stream>>>(a2h, W2, b2, dinv, bat, pool);
    final_k<<<NG, 64, 0, stream>>>(pool, bat, Wlin, blin, out);
}

// Round 14
// 210.784 us; speedup vs baseline: 1.0592x; 1.0365x over previous
//
#include <hip/hip_runtime.h>
#include <hip/hip_fp16.h>

#define NN 100000
#define NE 3200000
#define NG 2048
#define HD 64
#define BUKSZ 256         // nodes per bucket
#define NBUK 391          // ceil(NN / BUKSZ)
#define NB 512            // stage blocks
#define CHUNK 6250        // NE / NB exactly
#define CAP 9216          // padded edge capacity per bucket (mean 8192, sigma ~90)

// NOTE: int LDS atomics only (native ds ops). Float LDS atomicAdd is a CAS
// loop on this target (R8: 204.8M of them = 1342us) -- never use it.
// NOTE2 (R9): latency-bound gathers want max independent waves; do not make
// one wave process multiple nodes behind a block barrier.
// NOTE3 (R11): shfl with divergent srcLane under half-divergent loop bounds is
// undefined (reads exec-masked lanes). Index preload via wave-private LDS with
// UNIFORM trip counts instead (R13, verified).

// ---------------- init per-bucket cursors (absolute) ----------------

__global__ void init_k(int* __restrict__ bcur) {
    int t = blockIdx.x * blockDim.x + threadIdx.x;
    if (t <= NBUK) bcur[t] = t * CAP;
}

// ---------------- pass 1: block-local bucket sort -> padded bucket runs ----------------
// packed value: (dst & 255) << 17 | src   (src < 2^17)

__global__ __launch_bounds__(512) void stageA_k(
        const int* __restrict__ src, const int* __restrict__ dst,
        int* __restrict__ bcur, unsigned int* __restrict__ edges2) {
    __shared__ int hist[NBUK];
    __shared__ int exb[NBUK + 1];
    __shared__ int cur[NBUK];
    __shared__ int obase[NBUK];
    __shared__ int sc[512];
    __shared__ unsigned int svals[CHUNK];
    __shared__ unsigned short sbuk[CHUNK];   // bucket id per sorted slot (kills binary search)
    int b = blockIdx.x, t = threadIdx.x;
    int base = b * CHUNK;
    for (int i = t; i < NBUK; i += 512) hist[i] = 0;
    __syncthreads();
    for (int i = t; i < CHUNK; i += 512)
        atomicAdd(&hist[dst[base + i] >> 8], 1);
    __syncthreads();
    int v = (t < NBUK) ? hist[t] : 0;
    sc[t] = v;
    __syncthreads();
    for (int o = 1; o < 512; o <<= 1) {
        int u = (t >= o) ? sc[t - o] : 0;
        __syncthreads();
        sc[t] += u;
        __syncthreads();
    }
    if (t < NBUK) {
        int excl = sc[t] - v;
        exb[t] = excl;
        cur[t] = excl;
        obase[t] = v ? atomicAdd(&bcur[t], v) : 0;
    }
    if (t == 0) exb[NBUK] = CHUNK;
    __syncthreads();
    // scatter into LDS bucket-sorted order, recording bucket id per slot
    for (int i = t; i < CHUNK; i += 512) {
        int d = dst[base + i];
        int s = src[base + i];
        int bk = d >> 8;
        int pos = atomicAdd(&cur[bk], 1);
        svals[pos] = ((unsigned int)(d & 255) << 17) | (unsigned int)s;
        sbuk[pos] = (unsigned short)bk;
    }
    __syncthreads();
    // copy out: direct bucket lookup; coalesced runs
    for (int i = t; i < CHUNK; i += 512) {
        int lo = (int)sbuk[i];
        edges2[obase[lo] + (i - exb[lo])] = svals[i];
    }
}

// ---------------- pass 2: per-bucket fine sort (in-place) + row info + dinv + xs ----------------

__global__ __launch_bounds__(512) void build1_k(
        const int* __restrict__ bcur, const float4* __restrict__ x,
        unsigned int* __restrict__ edges2, int* __restrict__ row_beg,
        int* __restrict__ row_deg, float* __restrict__ dinv,
        float4* __restrict__ xs) {
    __shared__ unsigned int ebuf[CAP];   // 36 KB
    __shared__ int deg[BUKSZ];
    __shared__ int sc[BUKSZ];
    __shared__ int cur[BUKSZ];
    int k = blockIdx.x, t = threadIdx.x;
    int base = k * CAP;
    int len = bcur[k] - base;
    if (t < BUKSZ) deg[t] = 0;
    __syncthreads();
    for (int i = t; i < len; i += 512) {
        unsigned int pv = edges2[base + i];
        ebuf[i] = pv;
        atomicAdd(&deg[pv >> 17], 1);
    }
    __syncthreads();
    int v = 0;
    if (t < BUKSZ) { v = deg[t]; sc[t] = v; }
    __syncthreads();
    for (int o = 1; o < BUKSZ; o <<= 1) {
        int u = 0;
        if (t < BUKSZ && t >= o) u = sc[t - o];
        __syncthreads();
        if (t < BUKSZ && t >= o) sc[t] += u;
        __syncthreads();
    }
    if (t < BUKSZ) {
        int excl = sc[t] - v;
        cur[t] = excl;
        int node = k * BUKSZ + t;
        if (node < NN) {
            row_beg[node] = base + excl;
            row_deg[node] = v;
            float di = rsqrtf((float)v + 1.0f);
            dinv[node] = di;
            float4 xv = x[node];
            xs[node] = make_float4(xv.x * di, xv.y * di, xv.z * di, xv.w * di);
        }
    }
    __syncthreads();
    for (int i = t; i < len; i += 512) {
        unsigned int pv = ebuf[i];
        int pos = atomicAdd(&cur[pv >> 17], 1);
        edges2[base + pos] = pv & 0x1FFFFu;
    }
}

// ---------------- layer 1 FUSED: wave-per-node gather + W1 GEMM -> fp16 h1 ----------------

__global__ __launch_bounds__(256) void g1f_k(
        const float4* __restrict__ xs, const unsigned int* __restrict__ csr,
        const int* __restrict__ row_beg, const int* __restrict__ row_deg,
        const float* __restrict__ dinv, const float* __restrict__ W1,
        const float* __restrict__ b1, __half* __restrict__ h1) {
    int wid = (blockIdx.x * blockDim.x + threadIdx.x) >> 6;
    int lane = threadIdx.x & 63;
    if (wid >= NN) return;
    int beg = row_beg[wid], deg = row_deg[wid];
    float sx = 0.f, sy = 0.f, sz = 0.f, sw = 0.f;
    for (int e = beg + lane; e < beg + deg; e += 64) {
        float4 w = xs[csr[e]];
        sx += w.x; sy += w.y; sz += w.z; sw += w.w;
    }
#pragma unroll
    for (int o = 1; o < 64; o <<= 1) {
        sx += __shfl_xor(sx, o);
        sy += __shfl_xor(sy, o);
        sz += __shfl_xor(sz, o);
        sw += __shfl_xor(sw, o);
    }
    float di = dinv[wid];
    float4 self = xs[wid];
    float ax = (sx + self.x) * di;
    float ay = (sy + self.y) * di;
    float az = (sz + self.z) * di;
    float aw = (sw + self.w) * di;
    float v = ax * W1[lane] + ay * W1[64 + lane] + az * W1[128 + lane] + aw * W1[192 + lane] + b1[lane];
    v = fmaxf(v, 0.f) * di;
    h1[(size_t)wid * HD + lane] = __float2half_rn(v);
}

// ---------------- layer 2 gather: wave per node; indices via wave-private LDS ----------------
// a2h[d][h] = fp16( sum_{s in N(d)} h1[s][h] + h1[d][h] )   (fp32 accum, fp16 store)
// All loop bounds are wave-uniform (chunk); sidx reads are wave-uniform broadcasts.

__global__ __launch_bounds__(256) void gather2_k(
        const __half* __restrict__ h1, const unsigned int* __restrict__ csr,
        const int* __restrict__ row_beg, const int* __restrict__ row_deg,
        __half2* __restrict__ a2h) {
    __shared__ int sidx[4][64];          // per-wave index slice (wave-private)
    int wv = threadIdx.x >> 6;
    int wid = (blockIdx.x * blockDim.x + threadIdx.x) >> 6;
    int lane = threadIdx.x & 63;
    if (wid >= NN) return;
    int half = lane >> 5, f2 = lane & 31;
    int beg = row_beg[wid], deg = row_deg[wid];
    float ax = 0.f, ay = 0.f;
    int done = 0;
    while (done < deg) {
        int chunk = deg - done;
        if (chunk > 64) chunk = 64;
        if (lane < chunk) sidx[wv][lane] = (int)csr[beg + done + lane];  // 1 coalesced load
        int kb = 0;
        // 16 edges per half per iteration (32-edge block): deep MLP burst
        for (; kb + 31 < chunk; kb += 32) {
            int s[16];
#pragma unroll
            for (int j = 0; j < 16; ++j) s[j] = sidx[wv][kb + half + 2 * j];
            float2 f[16];
#pragma unroll
            for (int j = 0; j < 16; ++j)
                f[j] = __half22float2(((const __half2*)(h1 + (size_t)s[j] * HD))[f2]);
#pragma unroll
            for (int j = 0; j < 16; ++j) { ax += f[j].x; ay += f[j].y; }
        }
        for (; kb + 15 < chunk; kb += 16) {   // 8 edges per half
            int s[8];
#pragma unroll
            for (int j = 0; j < 8; ++j) s[j] = sidx[wv][kb + half + 2 * j];
            float2 f[8];
#pragma unroll
            for (int j = 0; j < 8; ++j)
                f[j] = __half22float2(((const __half2*)(h1 + (size_t)s[j] * HD))[f2]);
#pragma unroll
            for (int j = 0; j < 8; ++j) { ax += f[j].x; ay += f[j].y; }
        }
        for (; kb + 1 < chunk; kb += 2) {     // 1 edge per half
            int s0 = sidx[wv][kb + half];
            float2 f0 = __half22float2(((const __half2*)(h1 + (size_t)s0 * HD))[f2]);
            ax += f0.x; ay += f0.y;
        }
        if (kb < chunk && half == 0) {        // odd last edge: half0 only, no cross-lane
            int s0 = sidx[wv][kb];
            float2 f0 = __half22float2(((const __half2*)(h1 + (size_t)s0 * HD))[f2]);
            ax += f0.x; ay += f0.y;
        }
        done += chunk;
    }
    ax += __shfl_xor(ax, 32);
    ay += __shfl_xor(ay, 32);
    float2 self = __half22float2(((const __half2*)(h1 + (size_t)wid * HD))[f2]);
    ax += self.x; ay += self.y;
    if (half == 0)
        a2h[(size_t)wid * 32 + f2] = __floats2half2_rn(ax, ay);
}

// ---------------- combine2 + pool: 32 nodes per 512-thread block (fp16 a2 in) ----------------

__global__ __launch_bounds__(512) void combine2_pool_k(
        const __half* __restrict__ a2h, const float* __restrict__ W2,
        const float* __restrict__ b2, const float* __restrict__ dinv,
        const int* __restrict__ batch, float* __restrict__ pool) {
    __shared__ float w2s[HD * HD];     // 16 KB
    __shared__ float as2[32][HD];      // 8 KB
    __shared__ float vals[32][HD];     // 8 KB
    __shared__ int   bt[32];
    int tid = threadIdx.x;
    int wave = tid >> 6, lane = tid & 63;
    int base = blockIdx.x * 32;
    for (int i = tid; i < HD * HD; i += 512) w2s[i] = W2[i];
    for (int i = tid; i < 32 * HD; i += 512)
        as2[i >> 6][i & 63] = __half2float(a2h[(size_t)base * HD + i]);
    if (tid < 32) bt[tid] = batch[base + tid];
    __syncthreads();
#pragma unroll
    for (int r = 0; r < 4; ++r) {
        int nl = wave * 4 + r;
        float s = 0.f;
#pragma unroll
        for (int k = 0; k < HD; ++k) s = fmaf(as2[nl][k], w2s[k * HD + lane], s);
        float v = fmaxf(fmaf(dinv[base + nl], s, b2[lane]), 0.f);
        vals[nl][lane] = v;
    }
    __syncthreads();
    if (wave == 0) {   // batch-sorted flush: few native global float atomics
        int g = bt[0];
        float acc = 0.f;
        for (int i = 0; i < 32; ++i) {
            int bg = bt[i];
            if (bg != g) { atomicAdd(&pool[g * HD + lane], acc); acc = 0.f; g = bg; }
            acc += vals[i][lane];
        }
        atomicAdd(&pool[g * HD + lane], acc);
    }
}

__device__ __forceinline__ int lb_dev(const int* __restrict__ b, int n, int key) {
    int lo = 0, hi = n;
    while (lo < hi) {
        int mid = (lo + hi) >> 1;
        if (b[mid] < key) lo = mid + 1; else hi = mid;
    }
    return lo;
}

__global__ void final_k(const float* __restrict__ pool, const int* __restrict__ batch,
                        const float* __restrict__ Wlin, const float* __restrict__ blin,
                        float* __restrict__ out) {
    int g = blockIdx.x;
    int lane = threadIdx.x;
    int lo = lb_dev(batch, NN, g);
    int hi = lb_dev(batch, NN, g + 1);
    float cnt = (float)(hi - lo);
    float v = pool[g * HD + lane] * Wlin[lane];
#pragma unroll
    for (int off = 32; off > 0; off >>= 1) v += __shfl_down(v, off);
    if (lane == 0) out[g] = v / fmaxf(cnt, 1.0f) + blin[0];
}

// ---------------- launch ----------------

extern "C" void kernel_launch(void* const* d_in, const int* in_sizes, int n_in,
                              void* d_out, int out_size, void* d_ws, size_t ws_size,
                              hipStream_t stream) {
    const float* x    = (const float*)d_in[0];
    const int*   ei   = (const int*)d_in[1];
    const int*   bat  = (const int*)d_in[2];
    const float* W1   = (const float*)d_in[3];
    const float* b1   = (const float*)d_in[4];
    const float* W2   = (const float*)d_in[5];
    const float* b2   = (const float*)d_in[6];
    const float* Wlin = (const float*)d_in[7];
    const float* blin = (const float*)d_in[8];
    float* out = (float*)d_out;

    const int* src = ei;
    const int* dst = ei + NE;

    char* ws = (char*)d_ws;
    size_t off = 0;
    auto alloc = [&](size_t bytes) {
        char* p = ws + off;
        off += (bytes + 255) & ~(size_t)255;
        return p;
    };
    int*   bcur    = (int*)  alloc((NBUK + 1) * sizeof(int));
    int*   row_beg = (int*)  alloc(NN * sizeof(int));
    int*   row_deg = (int*)  alloc(NN * sizeof(int));
    float* dinv    = (float*)alloc(NN * sizeof(float));
    unsigned int* edges2 = (unsigned int*)alloc((size_t)NBUK * CAP * sizeof(unsigned int)); // 14.4 MB
    float4* xs     = (float4*)alloc((size_t)NN * sizeof(float4));
    __half* h1     = (__half*)alloc((size_t)NN * HD * sizeof(__half));
    __half* a2h    = (__half*)alloc((size_t)NN * HD * sizeof(__half));
    float* pool    = (float*)alloc((size_t)NG * HD * sizeof(float));
    (void)ws_size; (void)n_in; (void)in_sizes; (void)out_size;

    const int BLK = 256;
    const int gW = (NN * 64 + BLK - 1) / BLK;   // one wave per node

    // build: bucket runs -> in-place fine sort
    init_k<<<(NBUK + 1 + 255) / 256, 256, 0, stream>>>(bcur);
    stageA_k<<<NB, 512, 0, stream>>>(src, dst, bcur, edges2);
    build1_k<<<NBUK, 512, 0, stream>>>(bcur, (const float4*)x, edges2,
                                       row_beg, row_deg, dinv, xs);

    // layer 1 fused: gather + W1 GEMM -> fp16 h1
    g1f_k<<<gW, BLK, 0, stream>>>(xs, edges2, row_beg, row_deg, dinv, W1, b1, h1);

    // layer 2: LDS-index gather (16 edges/half in flight) -> fp16 a2
    gather2_k<<<gW, BLK, 0, stream>>>(h1, edges2, row_beg, row_deg, (__half2*)a2h);

    // combine + pool + readout
    hipMemsetAsync(pool, 0, (size_t)NG * HD * sizeof(float), stream);
    combine2_pool_k<<<NN / 32, 512, 0, stream>>>(a2h, W2, b2, dinv, bat, pool);
    final_k<<<NG, 64, 0, stream>>>(pool, bat, Wlin, blin, out);
}

// Round 15
// 202.654 us; speedup vs baseline: 1.1017x; 1.0401x over previous
//
#include <hip/hip_runtime.h>
#include <hip/hip_fp16.h>

#define NN 100000
#define NE 3200000
#define NG 2048
#define HD 64
#define BUKSZ 256         // nodes per bucket
#define NBUK 391          // ceil(NN / BUKSZ)
#define NB 512            // stage blocks
#define CHUNK 6250        // NE / NB exactly
#define CAP 9216          // padded edge capacity per bucket (mean 8192, sigma ~90)

// NOTE: int LDS atomics only (native ds ops). Float LDS atomicAdd is a CAS
// loop on this target (R8: 204.8M of them = 1342us) -- never use it.
// NOTE2 (R9): latency-bound gathers want max independent waves; do not make
// one wave process multiple nodes behind a block barrier.
// NOTE3 (R11): shfl with divergent srcLane under half-divergent loop bounds is
// undefined (reads exec-masked lanes). Index preload via wave-private LDS with
// UNIFORM trip counts instead (R13, verified).
// NOTE4 (R15): gather was VMEM-issue-bound at 4B/lane loads; 16B/lane loads
// cover 4 rows per instruction (4x fewer VMEM instrs).

// ---------------- init per-bucket cursors (absolute) ----------------

__global__ void init_k(int* __restrict__ bcur) {
    int t = blockIdx.x * blockDim.x + threadIdx.x;
    if (t <= NBUK) bcur[t] = t * CAP;
}

// ---------------- pass 1: block-local bucket sort -> padded bucket runs ----------------
// packed value: (dst & 255) << 17 | src   (src < 2^17)

__global__ __launch_bounds__(512) void stageA_k(
        const int* __restrict__ src, const int* __restrict__ dst,
        int* __restrict__ bcur, unsigned int* __restrict__ edges2) {
    __shared__ int hist[NBUK];
    __shared__ int exb[NBUK + 1];
    __shared__ int cur[NBUK];
    __shared__ int obase[NBUK];
    __shared__ int sc[512];
    __shared__ unsigned int svals[CHUNK];
    __shared__ unsigned short sbuk[CHUNK];   // bucket id per sorted slot
    int b = blockIdx.x, t = threadIdx.x;
    int base = b * CHUNK;
    for (int i = t; i < NBUK; i += 512) hist[i] = 0;
    __syncthreads();
    for (int i = t; i < CHUNK; i += 512)
        atomicAdd(&hist[dst[base + i] >> 8], 1);
    __syncthreads();
    int v = (t < NBUK) ? hist[t] : 0;
    sc[t] = v;
    __syncthreads();
    for (int o = 1; o < 512; o <<= 1) {
        int u = (t >= o) ? sc[t - o] : 0;
        __syncthreads();
        sc[t] += u;
        __syncthreads();
    }
    if (t < NBUK) {
        int excl = sc[t] - v;
        exb[t] = excl;
        cur[t] = excl;
        obase[t] = v ? atomicAdd(&bcur[t], v) : 0;
    }
    if (t == 0) exb[NBUK] = CHUNK;
    __syncthreads();
    for (int i = t; i < CHUNK; i += 512) {
        int d = dst[base + i];
        int s = src[base + i];
        int bk = d >> 8;
        int pos = atomicAdd(&cur[bk], 1);
        svals[pos] = ((unsigned int)(d & 255) << 17) | (unsigned int)s;
        sbuk[pos] = (unsigned short)bk;
    }
    __syncthreads();
    for (int i = t; i < CHUNK; i += 512) {
        int lo = (int)sbuk[i];
        edges2[obase[lo] + (i - exb[lo])] = svals[i];
    }
}

// ---------------- pass 2: per-bucket fine sort (in-place) + row info + dinv + xs ----------------

__global__ __launch_bounds__(512) void build1_k(
        const int* __restrict__ bcur, const float4* __restrict__ x,
        unsigned int* __restrict__ edges2, int* __restrict__ row_beg,
        int* __restrict__ row_deg, float* __restrict__ dinv,
        float4* __restrict__ xs) {
    __shared__ unsigned int ebuf[CAP];   // 36 KB
    __shared__ int deg[BUKSZ];
    __shared__ int sc[BUKSZ];
    __shared__ int cur[BUKSZ];
    int k = blockIdx.x, t = threadIdx.x;
    int base = k * CAP;
    int len = bcur[k] - base;
    if (t < BUKSZ) deg[t] = 0;
    __syncthreads();
    for (int i = t; i < len; i += 512) {
        unsigned int pv = edges2[base + i];
        ebuf[i] = pv;
        atomicAdd(&deg[pv >> 17], 1);
    }
    __syncthreads();
    int v = 0;
    if (t < BUKSZ) { v = deg[t]; sc[t] = v; }
    __syncthreads();
    for (int o = 1; o < BUKSZ; o <<= 1) {
        int u = 0;
        if (t < BUKSZ && t >= o) u = sc[t - o];
        __syncthreads();
        if (t < BUKSZ && t >= o) sc[t] += u;
        __syncthreads();
    }
    if (t < BUKSZ) {
        int excl = sc[t] - v;
        cur[t] = excl;
        int node = k * BUKSZ + t;
        if (node < NN) {
            row_beg[node] = base + excl;
            row_deg[node] = v;
            float di = rsqrtf((float)v + 1.0f);
            dinv[node] = di;
            float4 xv = x[node];
            xs[node] = make_float4(xv.x * di, xv.y * di, xv.z * di, xv.w * di);
        }
    }
    __syncthreads();
    for (int i = t; i < len; i += 512) {
        unsigned int pv = ebuf[i];
        int pos = atomicAdd(&cur[pv >> 17], 1);
        edges2[base + pos] = pv & 0x1FFFFu;
    }
}

// ---------------- layer 1 FUSED: wave-per-node gather + W1 GEMM -> fp16 h1 ----------------

__global__ __launch_bounds__(256) void g1f_k(
        const float4* __restrict__ xs, const unsigned int* __restrict__ csr,
        const int* __restrict__ row_beg, const int* __restrict__ row_deg,
        const float* __restrict__ dinv, const float* __restrict__ W1,
        const float* __restrict__ b1, __half* __restrict__ h1) {
    int wid = (blockIdx.x * blockDim.x + threadIdx.x) >> 6;
    int lane = threadIdx.x & 63;
    if (wid >= NN) return;
    int beg = row_beg[wid], deg = row_deg[wid];
    float sx = 0.f, sy = 0.f, sz = 0.f, sw = 0.f;
    for (int e = beg + lane; e < beg + deg; e += 64) {
        float4 w = xs[csr[e]];
        sx += w.x; sy += w.y; sz += w.z; sw += w.w;
    }
#pragma unroll
    for (int o = 1; o < 64; o <<= 1) {
        sx += __shfl_xor(sx, o);
        sy += __shfl_xor(sy, o);
        sz += __shfl_xor(sz, o);
        sw += __shfl_xor(sw, o);
    }
    float di = dinv[wid];
    float4 self = xs[wid];
    float ax = (sx + self.x) * di;
    float ay = (sy + self.y) * di;
    float az = (sz + self.z) * di;
    float aw = (sw + self.w) * di;
    float v = ax * W1[lane] + ay * W1[64 + lane] + az * W1[128 + lane] + aw * W1[192 + lane] + b1[lane];
    v = fmaxf(v, 0.f) * di;
    h1[(size_t)wid * HD + lane] = __float2half_rn(v);
}

// ---------------- layer 2 gather: wave per node; 16B/lane loads (4 rows/instr) ----------------
// Lane owns features [sub*8, sub*8+8), sub = lane&7. Edge per (half, g): 8 edges/iter.
// a2h[d][h] = fp16( sum_{s in N(d)} h1[s][h] + h1[d][h] )  (fp32 accum)

union H8 { int4 i4; __half2 h2[4]; };

__global__ __launch_bounds__(256) void gather2_k(
        const __half* __restrict__ h1, const unsigned int* __restrict__ csr,
        const int* __restrict__ row_beg, const int* __restrict__ row_deg,
        __half* __restrict__ a2h) {
    __shared__ int sidx[4][64];          // per-wave index slice (wave-private)
    int wv = threadIdx.x >> 6;
    int wid = (blockIdx.x * blockDim.x + threadIdx.x) >> 6;
    int lane = threadIdx.x & 63;
    if (wid >= NN) return;
    int half = lane >> 5;
    int g = (lane >> 3) & 3;
    int sub = lane & 7;
    int hg = half * 4 + g;               // edge slot 0..7 within an 8-edge block
    int beg = row_beg[wid], deg = row_deg[wid];
    float accx[4] = {0.f, 0.f, 0.f, 0.f};
    float accy[4] = {0.f, 0.f, 0.f, 0.f};
    int done = 0;
    while (done < deg) {
        int chunk = deg - done;
        if (chunk > 64) chunk = 64;
        if (lane < chunk) sidx[wv][lane] = (int)csr[beg + done + lane];  // 1 coalesced load
        int kb = 0;
        // 32 edges per iteration: 4 independent 16B loads per lane
        for (; kb + 31 < chunk; kb += 32) {
            int e0 = sidx[wv][kb + hg];
            int e1 = sidx[wv][kb + hg + 8];
            int e2 = sidx[wv][kb + hg + 16];
            int e3 = sidx[wv][kb + hg + 24];
            H8 r0, r1, r2, r3;
            r0.i4 = *(const int4*)(h1 + (size_t)e0 * HD + sub * 8);
            r1.i4 = *(const int4*)(h1 + (size_t)e1 * HD + sub * 8);
            r2.i4 = *(const int4*)(h1 + (size_t)e2 * HD + sub * 8);
            r3.i4 = *(const int4*)(h1 + (size_t)e3 * HD + sub * 8);
#pragma unroll
            for (int j = 0; j < 4; ++j) {
                float2 f0 = __half22float2(r0.h2[j]);
                float2 f1 = __half22float2(r1.h2[j]);
                float2 f2 = __half22float2(r2.h2[j]);
                float2 f3 = __half22float2(r3.h2[j]);
                accx[j] += (f0.x + f1.x) + (f2.x + f3.x);
                accy[j] += (f0.y + f1.y) + (f2.y + f3.y);
            }
        }
        for (; kb + 7 < chunk; kb += 8) {    // 8 edges: 1 load per lane
            int e0 = sidx[wv][kb + hg];
            H8 r0;
            r0.i4 = *(const int4*)(h1 + (size_t)e0 * HD + sub * 8);
#pragma unroll
            for (int j = 0; j < 4; ++j) {
                float2 f0 = __half22float2(r0.h2[j]);
                accx[j] += f0.x;
                accy[j] += f0.y;
            }
        }
        if (kb < chunk) {                    // tail <8: predicated per 8-lane group
            int e = kb + hg;
            if (e < chunk) {
                int e0 = sidx[wv][e];
                H8 r0;
                r0.i4 = *(const int4*)(h1 + (size_t)e0 * HD + sub * 8);
#pragma unroll
                for (int j = 0; j < 4; ++j) {
                    float2 f0 = __half22float2(r0.h2[j]);
                    accx[j] += f0.x;
                    accy[j] += f0.y;
                }
            }
        }
        done += chunk;
    }
    // reduce across groups (xor 8,16) and halves (xor 32); all lanes uniform
#pragma unroll
    for (int j = 0; j < 4; ++j) {
        accx[j] += __shfl_xor(accx[j], 8);
        accy[j] += __shfl_xor(accy[j], 8);
        accx[j] += __shfl_xor(accx[j], 16);
        accy[j] += __shfl_xor(accy[j], 16);
        accx[j] += __shfl_xor(accx[j], 32);
        accy[j] += __shfl_xor(accy[j], 32);
    }
    if (half == 0 && g == 0) {               // 8 lanes write the 128B row
        H8 sv, o;
        sv.i4 = *(const int4*)(h1 + (size_t)wid * HD + sub * 8);
#pragma unroll
        for (int j = 0; j < 4; ++j) {
            float2 fs = __half22float2(sv.h2[j]);
            o.h2[j] = __floats2half2_rn(accx[j] + fs.x, accy[j] + fs.y);
        }
        ((int4*)a2h)[(size_t)wid * 8 + sub] = o.i4;
    }
}

// ---------------- combine2 + pool: 32 nodes per 512-thread block (fp16 a2 in) ----------------

__global__ __launch_bounds__(512) void combine2_pool_k(
        const __half* __restrict__ a2h, const float* __restrict__ W2,
        const float* __restrict__ b2, const float* __restrict__ dinv,
        const int* __restrict__ batch, float* __restrict__ pool) {
    __shared__ float w2s[HD * HD];     // 16 KB
    __shared__ float as2[32][HD];      // 8 KB
    __shared__ float vals[32][HD];     // 8 KB
    __shared__ int   bt[32];
    int tid = threadIdx.x;
    int wave = tid >> 6, lane = tid & 63;
    int base = blockIdx.x * 32;
    for (int i = tid; i < HD * HD; i += 512) w2s[i] = W2[i];
    for (int i = tid; i < 32 * HD; i += 512)
        as2[i >> 6][i & 63] = __half2float(a2h[(size_t)base * HD + i]);
    if (tid < 32) bt[tid] = batch[base + tid];
    __syncthreads();
#pragma unroll
    for (int r = 0; r < 4; ++r) {
        int nl = wave * 4 + r;
        float s = 0.f;
#pragma unroll
        for (int k = 0; k < HD; ++k) s = fmaf(as2[nl][k], w2s[k * HD + lane], s);
        float v = fmaxf(fmaf(dinv[base + nl], s, b2[lane]), 0.f);
        vals[nl][lane] = v;
    }
    __syncthreads();
    if (wave == 0) {   // batch-sorted flush: few native global float atomics
        int g = bt[0];
        float acc = 0.f;
        for (int i = 0; i < 32; ++i) {
            int bg = bt[i];
            if (bg != g) { atomicAdd(&pool[g * HD + lane], acc); acc = 0.f; g = bg; }
            acc += vals[i][lane];
        }
        atomicAdd(&pool[g * HD + lane], acc);
    }
}

__device__ __forceinline__ int lb_dev(const int* __restrict__ b, int n, int key) {
    int lo = 0, hi = n;
    while (lo < hi) {
        int mid = (lo + hi) >> 1;
        if (b[mid] < key) lo = mid + 1; else hi = mid;
    }
    return lo;
}

__global__ void final_k(const float* __restrict__ pool, const int* __restrict__ batch,
                        const float* __restrict__ Wlin, const float* __restrict__ blin,
                        float* __restrict__ out) {
    int g = blockIdx.x;
    int lane = threadIdx.x;
    int lo = lb_dev(batch, NN, g);
    int hi = lb_dev(batch, NN, g + 1);
    float cnt = (float)(hi - lo);
    float v = pool[g * HD + lane] * Wlin[lane];
#pragma unroll
    for (int off = 32; off > 0; off >>= 1) v += __shfl_down(v, off);
    if (lane == 0) out[g] = v / fmaxf(cnt, 1.0f) + blin[0];
}

// ---------------- launch ----------------

extern "C" void kernel_launch(void* const* d_in, const int* in_sizes, int n_in,
                              void* d_out, int out_size, void* d_ws, size_t ws_size,
                              hipStream_t stream) {
    const float* x    = (const float*)d_in[0];
    const int*   ei   = (const int*)d_in[1];
    const int*   bat  = (const int*)d_in[2];
    const float* W1   = (const float*)d_in[3];
    const float* b1   = (const float*)d_in[4];
    const float* W2   = (const float*)d_in[5];
    const float* b2   = (const float*)d_in[6];
    const float* Wlin = (const float*)d_in[7];
    const float* blin = (const float*)d_in[8];
    float* out = (float*)d_out;

    const int* src = ei;
    const int* dst = ei + NE;

    char* ws = (char*)d_ws;
    size_t off = 0;
    auto alloc = [&](size_t bytes) {
        char* p = ws + off;
        off += (bytes + 255) & ~(size_t)255;
        return p;
    };
    int*   bcur    = (int*)  alloc((NBUK + 1) * sizeof(int));
    int*   row_beg = (int*)  alloc(NN * sizeof(int));
    int*   row_deg = (int*)  alloc(NN * sizeof(int));
    float* dinv    = (float*)alloc(NN * sizeof(float));
    unsigned int* edges2 = (unsigned int*)alloc((size_t)NBUK * CAP * sizeof(unsigned int)); // 14.4 MB
    float4* xs     = (float4*)alloc((size_t)NN * sizeof(float4));
    __half* h1     = (__half*)alloc((size_t)NN * HD * sizeof(__half));
    __half* a2h    = (__half*)alloc((size_t)NN * HD * sizeof(__half));
    float* pool    = (float*)alloc((size_t)NG * HD * sizeof(float));
    (void)ws_size; (void)n_in; (void)in_sizes; (void)out_size;

    const int BLK = 256;
    const int gW = (NN * 64 + BLK - 1) / BLK;   // one wave per node

    // build: bucket runs -> in-place fine sort
    init_k<<<(NBUK + 1 + 255) / 256, 256, 0, stream>>>(bcur);
    stageA_k<<<NB, 512, 0, stream>>>(src, dst, bcur, edges2);
    build1_k<<<NBUK, 512, 0, stream>>>(bcur, (const float4*)x, edges2,
                                       row_beg, row_deg, dinv, xs);

    // layer 1 fused: gather + W1 GEMM -> fp16 h1
    g1f_k<<<gW, BLK, 0, stream>>>(xs, edges2, row_beg, row_deg, dinv, W1, b1, h1);

    // layer 2: wide-load gather (4 rows per VMEM instr) -> fp16 a2
    gather2_k<<<gW, BLK, 0, stream>>>(h1, edges2, row_beg, row_deg, a2h);

    // combine + pool + readout
    hipMemsetAsync(pool, 0, (size_t)NG * HD * sizeof(float), stream);
    combine2_pool_k<<<NN / 32, 512, 0, stream>>>(a2h, W2, b2, dinv, bat, pool);
    final_k<<<NG, 64, 0, stream>>>(pool, bat, Wlin, blin, out);
}